// Round 5
// baseline (610.877 us; speedup 1.0000x reference)
//
#include <hip/hip_runtime.h>

// Sparse deconv (27-tap, 64->96ch) + BN + ReLU on MI355X.
// Row-compacted MFMA: per block (256 out rows) per tap, ballot-compact active
// (dst,src) pairs -> 16-row tiles; B-weights in registers per tap; D scattered
// into LDS fp32 accumulator via ds_add atomics. ~6.3x less MFMA than dense.

#define N_VOX   200000
#define INC     64
#define OUTC    96
#define NOFF    26
#define NBLK    782           // ceil(200000 / 256)
#define NPAD    200192        // NBLK*256, padded srcmap stride
#define EPSV    1e-5f

using bf16x8 = __attribute__((ext_vector_type(8))) short;
using f32x4  = __attribute__((ext_vector_type(4))) float;

__device__ inline unsigned short f2bf(float x) {
    union { float f; unsigned u; } v; v.f = x;
    unsigned r = (v.u + 0x7FFFu + ((v.u >> 16) & 1u)) >> 16;
    return (unsigned short)r;
}

__global__ void fill_src_kernel(const int* __restrict__ in_idx,
                                const int* __restrict__ out_idx,
                                int P, int* __restrict__ srcmap) {
    int idx = blockIdx.x * blockDim.x + threadIdx.x;
    if (idx >= NOFF * P) return;
    int dst = out_idx[idx];
    if (dst >= N_VOX) return;            // padded sink entries
    int k = idx / P;
    srcmap[(size_t)k * NPAD + dst] = in_idx[idx];
}

// Weights -> bf16, B-fragment order: Wb[m][s][ct][lane][e],
// k = s*32 + (lane>>4)*8 + e, col = ct*16 + (lane&15).
__global__ void wprep_kernel(const float* __restrict__ Wc,
                             const float* __restrict__ Woff,
                             unsigned short* __restrict__ Wb) {
    int t = blockIdx.x * blockDim.x + threadIdx.x;
    if (t >= 27 * 2 * 6 * 64) return;
    int lane = t & 63;
    int g    = t >> 6;              // m*12 + s*6 + ct
    int ct   = g % 6;
    int s    = (g / 6) % 2;
    int m    = g / 12;
    const float* W = (m == 26) ? Wc : (Woff + (size_t)m * INC * OUTC);
    int k0 = s * 32 + (lane >> 4) * 8;
    int c  = ct * 16 + (lane & 15);
    bf16x8 v;
    #pragma unroll
    for (int e = 0; e < 8; ++e)
        v[e] = (short)f2bf(W[(size_t)(k0 + e) * OUTC + c]);
    *(bf16x8*)(Wb + (size_t)t * 8) = v;
}

__global__ void fcvt_kernel(const float* __restrict__ feats,
                            unsigned short* __restrict__ featsb) {
    int i = blockIdx.x * blockDim.x + threadIdx.x;   // one per 8 elems
    if (i >= N_VOX * INC / 8) return;
    const float4* src = (const float4*)feats + (size_t)i * 2;
    float4 f0 = src[0], f1 = src[1];
    bf16x8 v;
    v[0] = (short)f2bf(f0.x); v[1] = (short)f2bf(f0.y);
    v[2] = (short)f2bf(f0.z); v[3] = (short)f2bf(f0.w);
    v[4] = (short)f2bf(f1.x); v[5] = (short)f2bf(f1.y);
    v[6] = (short)f2bf(f1.z); v[7] = (short)f2bf(f1.w);
    *(bf16x8*)(featsb + (size_t)i * 8) = v;
}

template<int STAGE_BF16>
__global__ __launch_bounds__(512, 2)
void conv_sparse_kernel(const unsigned short* __restrict__ featsb,
                        const unsigned short* __restrict__ Wb,
                        const int* __restrict__ srcmap,
                        float* __restrict__ outf,
                        unsigned short* __restrict__ stg,
                        float* __restrict__ pstats) {
    __shared__ float acc[256][97];          // 99.3 KB, +1 col pad (stats reads)
    __shared__ unsigned wlist[8][256];      // 8 KB, per-wave compacted pairs

    const int t     = threadIdx.x;
    const int wid   = t >> 6;
    const int lane  = t & 63;
    const int blk   = blockIdx.x;
    const int rbase = blk * 256;
    const int row16 = lane & 15;
    const int kgrp  = lane >> 4;

    // early srcmap prefetch for this wave's first tap (covered by zero+center)
    int sm[4];
    if (wid < NOFF) {
        #pragma unroll
        for (int c = 0; c < 4; ++c)
            sm[c] = srcmap[(size_t)wid * NPAD + rbase + c * 64 + lane];
    }

    for (int i = t; i < 256 * 97; i += 512) ((float*)acc)[i] = 0.f;
    __syncthreads();

    // ---- center tap (identity map): 2 dense tiles per wave ----
    {
        const unsigned short* wb = Wb + (size_t)26 * 6144;
        bf16x8 B0[6], B1[6];
        #pragma unroll
        for (int ct = 0; ct < 6; ++ct) {
            B0[ct] = *(const bf16x8*)(wb + (size_t)ct * 512 + lane * 8);
            B1[ct] = *(const bf16x8*)(wb + (size_t)(6 + ct) * 512 + lane * 8);
        }
        #pragma unroll
        for (int it = 0; it < 2; ++it) {
            int e = wid * 32 + it * 16 + row16;
            int srow = rbase + e;
            int src = srow < N_VOX ? srow : N_VOX;        // pad row = zeros
            const unsigned short* fr = featsb + (size_t)src * INC + kgrp * 8;
            bf16x8 a0 = *(const bf16x8*)fr;
            bf16x8 a1 = *(const bf16x8*)(fr + 32);
            f32x4 d[6] = {};
            #pragma unroll
            for (int ct = 0; ct < 6; ++ct) {
                d[ct] = __builtin_amdgcn_mfma_f32_16x16x32_bf16(a0, B0[ct], d[ct], 0, 0, 0);
                d[ct] = __builtin_amdgcn_mfma_f32_16x16x32_bf16(a1, B1[ct], d[ct], 0, 0, 0);
            }
            int db = wid * 32 + it * 16 + kgrp * 4;
            #pragma unroll
            for (int ct = 0; ct < 6; ++ct) {
                atomicAdd(&acc[db + 0][ct * 16 + row16], d[ct][0]);
                atomicAdd(&acc[db + 1][ct * 16 + row16], d[ct][1]);
                atomicAdd(&acc[db + 2][ct * 16 + row16], d[ct][2]);
                atomicAdd(&acc[db + 3][ct * 16 + row16], d[ct][3]);
            }
        }
    }

    // ---- off-center taps: wave handles taps wid, wid+8, wid+16, (wid+24) ----
    for (int tap = wid; tap < NOFF; tap += 8) {
        // srcmap prefetch for next owned tap
        int smn[4];
        if (tap + 8 < NOFF) {
            #pragma unroll
            for (int c = 0; c < 4; ++c)
                smn[c] = srcmap[(size_t)(tap + 8) * NPAD + rbase + c * 64 + lane];
        }
        // B fragments for this tap -> registers (reused across tiles)
        const unsigned short* wb = Wb + (size_t)tap * 6144;
        bf16x8 B0[6], B1[6];
        #pragma unroll
        for (int ct = 0; ct < 6; ++ct) {
            B0[ct] = *(const bf16x8*)(wb + (size_t)ct * 512 + lane * 8);
            B1[ct] = *(const bf16x8*)(wb + (size_t)(6 + ct) * 512 + lane * 8);
        }
        // compact active (dst,src) pairs: pk = src<<8 | dst_local
        int base = 0;
        #pragma unroll
        for (int c = 0; c < 4; ++c) {
            int s = sm[c];
            unsigned long long m = __ballot(s >= 0);
            int rank = __popcll(m & ((1ull << lane) - 1ull));
            if (s >= 0) wlist[wid][base + rank] = ((unsigned)s << 8) | (unsigned)(c * 64 + lane);
            base += (int)__popcll(m);
        }
        const int nt = base;
        const int ntile = (nt + 15) >> 4;

        // tile loop, 1-deep gather prefetch; pads gather zero row, add to row 0
        unsigned pkN = (unsigned)N_VOX << 8;
        bf16x8 a0N = {}, a1N = {};
        if (ntile > 0) {
            int e = row16;
            pkN = (e < nt) ? wlist[wid][e] : ((unsigned)N_VOX << 8);
            const unsigned short* fr = featsb + (size_t)(pkN >> 8) * INC + kgrp * 8;
            a0N = *(const bf16x8*)fr;
            a1N = *(const bf16x8*)(fr + 32);
        }
        for (int i = 0; i < ntile; ++i) {
            unsigned pk = pkN;
            bf16x8 a0 = a0N, a1 = a1N;
            if (i + 1 < ntile) {
                int e = (i + 1) * 16 + row16;
                pkN = (e < nt) ? wlist[wid][e] : ((unsigned)N_VOX << 8);
                const unsigned short* fr = featsb + (size_t)(pkN >> 8) * INC + kgrp * 8;
                a0N = *(const bf16x8*)fr;
                a1N = *(const bf16x8*)(fr + 32);
            }
            f32x4 d[6] = {};
            #pragma unroll
            for (int ct = 0; ct < 6; ++ct) {
                d[ct] = __builtin_amdgcn_mfma_f32_16x16x32_bf16(a0, B0[ct], d[ct], 0, 0, 0);
                d[ct] = __builtin_amdgcn_mfma_f32_16x16x32_bf16(a1, B1[ct], d[ct], 0, 0, 0);
            }
            int dv = (int)(pk & 255u);
            int d0 = __shfl(dv, kgrp * 4 + 0);
            int d1 = __shfl(dv, kgrp * 4 + 1);
            int d2 = __shfl(dv, kgrp * 4 + 2);
            int d3 = __shfl(dv, kgrp * 4 + 3);
            #pragma unroll
            for (int ct = 0; ct < 6; ++ct) {
                atomicAdd(&acc[d0][ct * 16 + row16], d[ct][0]);
                atomicAdd(&acc[d1][ct * 16 + row16], d[ct][1]);
                atomicAdd(&acc[d2][ct * 16 + row16], d[ct][2]);
                atomicAdd(&acc[d3][ct * 16 + row16], d[ct][3]);
            }
        }
        if (tap + 8 < NOFF) {
            #pragma unroll
            for (int c = 0; c < 4; ++c) sm[c] = smn[c];
        }
    }
    __syncthreads();

    // ---- BN partial stats (column sums; stride 97 -> conflict-free) ----
    const int rmax = min(256, N_VOX - rbase);
    if (t < 96) {
        float s = 0.f, q = 0.f;
        for (int r = 0; r < rmax; ++r) {
            float v = acc[r][t];
            s += v;
            q = fmaf(v, v, q);
        }
        pstats[(size_t)t * NBLK + blk] = s;
        pstats[(size_t)(96 + t) * NBLK + blk] = q;
    }

    // ---- store conv output (each wave: its 32 rows; lanes 0..47 x 2 ch) ----
    if (lane < 48) {
        for (int r = wid * 32; r < wid * 32 + 32; ++r) {
            int grow = rbase + r;
            if (grow < N_VOX) {
                float v0 = acc[r][2 * lane];
                float v1 = acc[r][2 * lane + 1];
                if (STAGE_BF16) {
                    unsigned u = (unsigned)f2bf(v0) | ((unsigned)f2bf(v1) << 16);
                    *(unsigned*)(stg + (size_t)grow * OUTC + 2 * lane) = u;
                } else {
                    *(float2*)(outf + (size_t)grow * OUTC + 2 * lane) = make_float2(v0, v1);
                }
            }
        }
    }
}

__global__ void stats_reduce_kernel(const float* __restrict__ pstats,
                                    const float* __restrict__ gamma,
                                    const float* __restrict__ beta,
                                    float* __restrict__ scsh) {
    int c = blockIdx.x;               // 0..95
    int t = threadIdx.x;
    float s = 0.f, q = 0.f;
    for (int i = t; i < NBLK; i += 256) {
        s += pstats[(size_t)c * NBLK + i];
        q += pstats[(size_t)(96 + c) * NBLK + i];
    }
    #pragma unroll
    for (int d = 1; d < 64; d <<= 1) {
        s += __shfl_xor(s, d);
        q += __shfl_xor(q, d);
    }
    __shared__ float rs[4], rq[4];
    if ((t & 63) == 0) { rs[t >> 6] = s; rq[t >> 6] = q; }
    __syncthreads();
    if (t == 0) {
        s = rs[0] + rs[1] + rs[2] + rs[3];
        q = rq[0] + rq[1] + rq[2] + rq[3];
        float inv_n = 1.0f / (float)N_VOX;
        float mean = s * inv_n;
        float var  = q * inv_n - mean * mean;
        float sc   = gamma[c] * rsqrtf(var + EPSV);
        scsh[c]      = sc;
        scsh[96 + c] = beta[c] - mean * sc;
    }
}

__global__ void apply_bn_bf16_kernel(const unsigned short* __restrict__ stg,
                                     float* __restrict__ out,
                                     const float* __restrict__ scsh) {
    __shared__ float sc[OUTC], sh[OUTC];
    int t = threadIdx.x;
    if (t < OUTC) { sc[t] = scsh[t]; sh[t] = scsh[96 + t]; }
    __syncthreads();
    const int total8 = N_VOX * OUTC / 8;
    for (int i = blockIdx.x * blockDim.x + t; i < total8; i += gridDim.x * blockDim.x) {
        bf16x8 v = *(const bf16x8*)(stg + (size_t)i * 8);
        int c = (i % 12) * 8;
        float o[8];
        #pragma unroll
        for (int j = 0; j < 8; ++j) {
            union { unsigned u; float f; } w; w.u = (unsigned)(unsigned short)v[j] << 16;
            o[j] = fmaxf(fmaf(w.f, sc[c + j], sh[c + j]), 0.f);
        }
        float4* dst = (float4*)(out + (size_t)i * 8);
        dst[0] = make_float4(o[0], o[1], o[2], o[3]);
        dst[1] = make_float4(o[4], o[5], o[6], o[7]);
    }
}

__global__ void apply_bn_fp32_kernel(float* __restrict__ out,
                                     const float* __restrict__ scsh) {
    __shared__ float sc[OUTC], sh[OUTC];
    int t = threadIdx.x;
    if (t < OUTC) { sc[t] = scsh[t]; sh[t] = scsh[96 + t]; }
    __syncthreads();
    const int total4 = N_VOX * OUTC / 4;
    for (int i = blockIdx.x * blockDim.x + t; i < total4; i += gridDim.x * blockDim.x) {
        float4 v = ((float4*)out)[i];
        int c = (i * 4) % OUTC;
        v.x = fmaxf(fmaf(v.x, sc[c    ], sh[c    ]), 0.f);
        v.y = fmaxf(fmaf(v.y, sc[c + 1], sh[c + 1]), 0.f);
        v.z = fmaxf(fmaf(v.z, sc[c + 2], sh[c + 2]), 0.f);
        v.w = fmaxf(fmaf(v.w, sc[c + 3], sh[c + 3]), 0.f);
        ((float4*)out)[i] = v;
    }
}

extern "C" void kernel_launch(void* const* d_in, const int* in_sizes, int n_in,
                              void* d_out, int out_size, void* d_ws, size_t ws_size,
                              hipStream_t stream) {
    const float* feats   = (const float*)d_in[0];
    const float* Wc      = (const float*)d_in[1];
    const float* Woff    = (const float*)d_in[2];
    const float* gamma   = (const float*)d_in[3];
    const float* beta    = (const float*)d_in[4];
    const int*   in_idx  = (const int*)d_in[5];
    const int*   out_idx = (const int*)d_in[6];
    const int P = in_sizes[5] / NOFF;

    char* w = (char*)d_ws;
    int* srcmap = (int*)w;                   w += (size_t)NOFF * NPAD * 4;    // 20.82 MB
    unsigned short* Wb = (unsigned short*)w; w += (size_t)27 * 6144 * 2;      // 332 KB
    float* pstats = (float*)w;               w += (size_t)192 * NBLK * 4;     // 0.6 MB
    float* scsh = (float*)w;                 w += 256 * 4;
    unsigned short* featsb = (unsigned short*)w;
    w += (size_t)(N_VOX + 1) * INC * 2;                                        // 25.6 MB (+pad row)
    unsigned short* stg = (unsigned short*)w;
    size_t need_stg = (size_t)(w - (char*)d_ws) + (size_t)N_VOX * OUTC * 2;   // +38.4 MB
    bool use_stg = (ws_size >= need_stg);

    hipMemsetAsync(srcmap, 0xFF, (size_t)NOFF * NPAD * 4, stream);
    hipMemsetAsync(featsb + (size_t)N_VOX * INC, 0, INC * 2, stream);         // zero pad row
    fill_src_kernel<<<(NOFF * P + 255) / 256, 256, 0, stream>>>(in_idx, out_idx, P, srcmap);
    wprep_kernel<<<(27 * 2 * 6 * 64 + 255) / 256, 256, 0, stream>>>(Wc, Woff, Wb);
    fcvt_kernel<<<(N_VOX * INC / 8 + 255) / 256, 256, 0, stream>>>(feats, featsb);

    float* out = (float*)d_out;
    if (use_stg) {
        conv_sparse_kernel<1><<<NBLK, 512, 0, stream>>>(featsb, Wb, srcmap, out, stg, pstats);
        stats_reduce_kernel<<<96, 256, 0, stream>>>(pstats, gamma, beta, scsh);
        apply_bn_bf16_kernel<<<2048, 256, 0, stream>>>(stg, out, scsh);
    } else {
        conv_sparse_kernel<0><<<NBLK, 512, 0, stream>>>(featsb, Wb, srcmap, out, stg, pstats);
        stats_reduce_kernel<<<96, 256, 0, stream>>>(pstats, gamma, beta, scsh);
        apply_bn_fp32_kernel<<<2048, 256, 0, stream>>>(out, scsh);
    }
}

// Round 6
// 141.464 us; speedup vs baseline: 4.3182x; 4.3182x over previous
//
#include <hip/hip_runtime.h>

// Sparse deconv (27-tap, 64->96ch) + BN + ReLU on MI355X.
// Barrier-free conv: B weights in registers per tap (no LDS, no __syncthreads
// in main loop), exec-masked sparse gathers, 2-deep srcmap / 1-deep gather
// prefetch in plain HIP. bf16 conv-output staging; fused BN+ReLU apply.

#define N_VOX   200000
#define INC     64
#define OUTC    96
#define NOFF    26
#define NBLK    782           // ceil(200000 / 256)
#define NPAD    200192        // NBLK*256, padded srcmap stride
#define EPSV    1e-5f

using bf16x8 = __attribute__((ext_vector_type(8))) short;
using f32x4  = __attribute__((ext_vector_type(4))) float;

__device__ inline unsigned short f2bf(float x) {
    union { float f; unsigned u; } v; v.f = x;
    unsigned r = (v.u + 0x7FFFu + ((v.u >> 16) & 1u)) >> 16;
    return (unsigned short)r;
}

__global__ void fill_src_kernel(const int* __restrict__ in_idx,
                                const int* __restrict__ out_idx,
                                int P, int* __restrict__ srcmap) {
    int idx = blockIdx.x * blockDim.x + threadIdx.x;
    if (idx >= NOFF * P) return;
    int dst = out_idx[idx];
    if (dst >= N_VOX) return;            // padded sink entries
    int k = idx / P;
    srcmap[(size_t)k * NPAD + dst] = in_idx[idx];
}

// Weights -> bf16, B-fragment order: Wb[m][s][ct][lane][e],
// k = s*32 + (lane>>4)*8 + e, col = ct*16 + (lane&15).
__global__ void wprep_kernel(const float* __restrict__ Wc,
                             const float* __restrict__ Woff,
                             unsigned short* __restrict__ Wb) {
    int t = blockIdx.x * blockDim.x + threadIdx.x;
    if (t >= 27 * 2 * 6 * 64) return;
    int lane = t & 63;
    int g    = t >> 6;              // m*12 + s*6 + ct
    int ct   = g % 6;
    int s    = (g / 6) % 2;
    int m    = g / 12;
    const float* W = (m == 26) ? Wc : (Woff + (size_t)m * INC * OUTC);
    int k0 = s * 32 + (lane >> 4) * 8;
    int c  = ct * 16 + (lane & 15);
    bf16x8 v;
    #pragma unroll
    for (int e = 0; e < 8; ++e)
        v[e] = (short)f2bf(W[(size_t)(k0 + e) * OUTC + c]);
    *(bf16x8*)(Wb + (size_t)t * 8) = v;
}

__global__ void fcvt_kernel(const float* __restrict__ feats,
                            unsigned short* __restrict__ featsb) {
    int i = blockIdx.x * blockDim.x + threadIdx.x;   // one per 8 elems
    if (i >= N_VOX * INC / 8) return;
    const float4* src = (const float4*)feats + (size_t)i * 2;
    float4 f0 = src[0], f1 = src[1];
    bf16x8 v;
    v[0] = (short)f2bf(f0.x); v[1] = (short)f2bf(f0.y);
    v[2] = (short)f2bf(f0.z); v[3] = (short)f2bf(f0.w);
    v[4] = (short)f2bf(f1.x); v[5] = (short)f2bf(f1.y);
    v[6] = (short)f2bf(f1.z); v[7] = (short)f2bf(f1.w);
    *(bf16x8*)(featsb + (size_t)i * 8) = v;
}

// tap order: idx 0 -> center (Wb[26], identity src), idx i>=1 -> offset i-1.
// No LDS / no barriers in main loop: B in registers, exec-masked gathers,
// compiler-scheduled pipeline.
template<int STAGE_BF16>
__global__ __launch_bounds__(256, 2)
void conv_mfma_kernel(const unsigned short* __restrict__ featsb,
                      const unsigned short* __restrict__ Wb,
                      const int* __restrict__ srcmap,
                      float* __restrict__ outf,
                      unsigned short* __restrict__ stg,
                      float* __restrict__ pstats) {
    __shared__ float sred[768];               // stats only (post-loop)

    const int t     = threadIdx.x;
    const int wid   = t >> 6;
    const int lane  = t & 63;
    const int blk   = blockIdx.x;
    const int rbase = blk * 256 + wid * 64;   // this wave's 64 output rows
    const int row16 = lane & 15;
    const int kgrp  = lane >> 4;              // 0..3

    f32x4  acc[4][6] = {};
    bf16x8 aC[4][2], aN[4][2];
    int smC[4], smN[4];
    int hasC, hasN;

    // ---- prologue: srcmap for tap 1 (offset 0); gather center rows ----
    #pragma unroll
    for (int rt = 0; rt < 4; ++rt)
        smC[rt] = srcmap[rbase + rt * 16 + row16];
    #pragma unroll
    for (int rt = 0; rt < 4; ++rt) {
        int row = rbase + rt * 16 + row16;
        int src = row < N_VOX ? row : N_VOX;              // pad row = zeros
        const unsigned short* fr = featsb + (size_t)src * INC + kgrp * 8;
        aC[rt][0] = *(const bf16x8*)fr;
        aC[rt][1] = *(const bf16x8*)(fr + 32);
    }
    hasC = 0xF;

    #pragma unroll 1
    for (int idx = 0; idx < 27; ++idx) {
        // 1. srcmap prefetch for tap idx+2 (offset idx+1)
        if (idx < 25) {
            #pragma unroll
            for (int rt = 0; rt < 4; ++rt)
                smN[rt] = srcmap[(size_t)(idx + 1) * NPAD + rbase + rt * 16 + row16];
        }

        // 2. exec-masked gather of A for tap idx+1 (offset idx)
        if (idx < 26) {
            int h = 0;
            #pragma unroll
            for (int rt = 0; rt < 4; ++rt) {
                int s = smC[rt];
                if (__ballot(s >= 0)) h |= (1 << rt);
                bf16x8 g0 = {}, g1 = {};
                if (s >= 0) {
                    const unsigned short* fr = featsb + (size_t)s * INC + kgrp * 8;
                    g0 = *(const bf16x8*)fr;
                    g1 = *(const bf16x8*)(fr + 32);
                }
                aN[rt][0] = g0; aN[rt][1] = g1;
            }
            hasN = __builtin_amdgcn_readfirstlane(h);
        } else {
            hasN = 0;
        }

        // 3. B for current tap -> registers (uniform pattern, L1/L2-hit)
        const unsigned short* wb = Wb + (size_t)(idx == 0 ? 26 : idx - 1) * 6144;
        bf16x8 B0[6], B1[6];
        #pragma unroll
        for (int ct = 0; ct < 6; ++ct) {
            B0[ct] = *(const bf16x8*)(wb + (size_t)ct * 512 + lane * 8);
            B1[ct] = *(const bf16x8*)(wb + (size_t)(6 + ct) * 512 + lane * 8);
        }

        // 4. MFMA current tap, per-rt skip
        #pragma unroll
        for (int rt = 0; rt < 4; ++rt) {
            if (hasC & (1 << rt)) {
                #pragma unroll
                for (int ct = 0; ct < 6; ++ct) {
                    acc[rt][ct] = __builtin_amdgcn_mfma_f32_16x16x32_bf16(aC[rt][0], B0[ct], acc[rt][ct], 0, 0, 0);
                    acc[rt][ct] = __builtin_amdgcn_mfma_f32_16x16x32_bf16(aC[rt][1], B1[ct], acc[rt][ct], 0, 0, 0);
                }
            }
        }

        // 5. roll pipeline registers
        #pragma unroll
        for (int rt = 0; rt < 4; ++rt) {
            aC[rt][0] = aN[rt][0]; aC[rt][1] = aN[rt][1];
            smC[rt] = (idx < 25) ? smN[rt] : -1;
        }
        hasC = hasN;
    }

    // ---- BN partial stats: lane -> wave shfl -> LDS cross-wave ----
    float s6[6], q6[6];
    #pragma unroll
    for (int ct = 0; ct < 6; ++ct) {
        float s = 0.f, q = 0.f;
        #pragma unroll
        for (int rt = 0; rt < 4; ++rt) {
            f32x4 a = acc[rt][ct];
            s += a[0] + a[1] + a[2] + a[3];
            q += a[0]*a[0] + a[1]*a[1] + a[2]*a[2] + a[3]*a[3];
        }
        s += __shfl_xor(s, 16); q += __shfl_xor(q, 16);
        s += __shfl_xor(s, 32); q += __shfl_xor(q, 32);
        s6[ct] = s; q6[ct] = q;
    }
    if (lane < 16) {
        #pragma unroll
        for (int ct = 0; ct < 6; ++ct) {
            sred[wid * 96 + ct * 16 + lane]       = s6[ct];
            sred[384 + wid * 96 + ct * 16 + lane] = q6[ct];
        }
    }
    __syncthreads();
    if (t < 96) {
        float s = sred[t] + sred[96 + t] + sred[192 + t] + sred[288 + t];
        pstats[(size_t)t * NBLK + blk] = s;
    } else if (t < 192) {
        int c = t - 96;
        float q = sred[384 + c] + sred[480 + c] + sred[576 + c] + sred[672 + c];
        pstats[(size_t)(96 + c) * NBLK + blk] = q;
    }

    // ---- store conv output ----
    #pragma unroll
    for (int rt = 0; rt < 4; ++rt) {
        #pragma unroll
        for (int ct = 0; ct < 6; ++ct) {
            #pragma unroll
            for (int j = 0; j < 4; ++j) {
                int row = rbase + rt * 16 + kgrp * 4 + j;
                if (row < N_VOX) {
                    if (STAGE_BF16)
                        stg[(size_t)row * OUTC + ct * 16 + row16] = f2bf(acc[rt][ct][j]);
                    else
                        outf[(size_t)row * OUTC + ct * 16 + row16] = acc[rt][ct][j];
                }
            }
        }
    }
}

__global__ void stats_reduce_kernel(const float* __restrict__ pstats,
                                    const float* __restrict__ gamma,
                                    const float* __restrict__ beta,
                                    float* __restrict__ scsh) {
    int c = blockIdx.x;               // 0..95
    int t = threadIdx.x;
    float s = 0.f, q = 0.f;
    for (int i = t; i < NBLK; i += 256) {
        s += pstats[(size_t)c * NBLK + i];
        q += pstats[(size_t)(96 + c) * NBLK + i];
    }
    #pragma unroll
    for (int d = 1; d < 64; d <<= 1) {
        s += __shfl_xor(s, d);
        q += __shfl_xor(q, d);
    }
    __shared__ float rs[4], rq[4];
    if ((t & 63) == 0) { rs[t >> 6] = s; rq[t >> 6] = q; }
    __syncthreads();
    if (t == 0) {
        s = rs[0] + rs[1] + rs[2] + rs[3];
        q = rq[0] + rq[1] + rq[2] + rq[3];
        float inv_n = 1.0f / (float)N_VOX;
        float mean = s * inv_n;
        float var  = q * inv_n - mean * mean;
        float sc   = gamma[c] * rsqrtf(var + EPSV);
        scsh[c]      = sc;
        scsh[96 + c] = beta[c] - mean * sc;
    }
}

__global__ void apply_bn_bf16_kernel(const unsigned short* __restrict__ stg,
                                     float* __restrict__ out,
                                     const float* __restrict__ scsh) {
    __shared__ float sc[OUTC], sh[OUTC];
    int t = threadIdx.x;
    if (t < OUTC) { sc[t] = scsh[t]; sh[t] = scsh[96 + t]; }
    __syncthreads();
    const int total8 = N_VOX * OUTC / 8;
    for (int i = blockIdx.x * blockDim.x + t; i < total8; i += gridDim.x * blockDim.x) {
        bf16x8 v = *(const bf16x8*)(stg + (size_t)i * 8);
        int c = (i % 12) * 8;
        float o[8];
        #pragma unroll
        for (int j = 0; j < 8; ++j) {
            union { unsigned u; float f; } w; w.u = (unsigned)(unsigned short)v[j] << 16;
            o[j] = fmaxf(fmaf(w.f, sc[c + j], sh[c + j]), 0.f);
        }
        float4* dst = (float4*)(out + (size_t)i * 8);
        dst[0] = make_float4(o[0], o[1], o[2], o[3]);
        dst[1] = make_float4(o[4], o[5], o[6], o[7]);
    }
}

__global__ void apply_bn_fp32_kernel(float* __restrict__ out,
                                     const float* __restrict__ scsh) {
    __shared__ float sc[OUTC], sh[OUTC];
    int t = threadIdx.x;
    if (t < OUTC) { sc[t] = scsh[t]; sh[t] = scsh[96 + t]; }
    __syncthreads();
    const int total4 = N_VOX * OUTC / 4;
    for (int i = blockIdx.x * blockDim.x + t; i < total4; i += gridDim.x * blockDim.x) {
        float4 v = ((float4*)out)[i];
        int c = (i * 4) % OUTC;
        v.x = fmaxf(fmaf(v.x, sc[c    ], sh[c    ]), 0.f);
        v.y = fmaxf(fmaf(v.y, sc[c + 1], sh[c + 1]), 0.f);
        v.z = fmaxf(fmaf(v.z, sc[c + 2], sh[c + 2]), 0.f);
        v.w = fmaxf(fmaf(v.w, sc[c + 3], sh[c + 3]), 0.f);
        ((float4*)out)[i] = v;
    }
}

extern "C" void kernel_launch(void* const* d_in, const int* in_sizes, int n_in,
                              void* d_out, int out_size, void* d_ws, size_t ws_size,
                              hipStream_t stream) {
    const float* feats   = (const float*)d_in[0];
    const float* Wc      = (const float*)d_in[1];
    const float* Woff    = (const float*)d_in[2];
    const float* gamma   = (const float*)d_in[3];
    const float* beta    = (const float*)d_in[4];
    const int*   in_idx  = (const int*)d_in[5];
    const int*   out_idx = (const int*)d_in[6];
    const int P = in_sizes[5] / NOFF;

    char* w = (char*)d_ws;
    int* srcmap = (int*)w;                   w += (size_t)NOFF * NPAD * 4;    // 20.82 MB
    unsigned short* Wb = (unsigned short*)w; w += (size_t)27 * 6144 * 2;      // 332 KB
    float* pstats = (float*)w;               w += (size_t)192 * NBLK * 4;     // 0.6 MB
    float* scsh = (float*)w;                 w += 256 * 4;
    unsigned short* featsb = (unsigned short*)w;
    w += (size_t)(N_VOX + 1) * INC * 2;                                        // 25.6 MB (+pad row)
    unsigned short* stg = (unsigned short*)w;
    size_t need_stg = (size_t)(w - (char*)d_ws) + (size_t)N_VOX * OUTC * 2;   // +38.4 MB
    bool use_stg = (ws_size >= need_stg);

    hipMemsetAsync(srcmap, 0xFF, (size_t)NOFF * NPAD * 4, stream);
    hipMemsetAsync(featsb + (size_t)N_VOX * INC, 0, INC * 2, stream);         // zero pad row
    fill_src_kernel<<<(NOFF * P + 255) / 256, 256, 0, stream>>>(in_idx, out_idx, P, srcmap);
    wprep_kernel<<<(27 * 2 * 6 * 64 + 255) / 256, 256, 0, stream>>>(Wc, Woff, Wb);
    fcvt_kernel<<<(N_VOX * INC / 8 + 255) / 256, 256, 0, stream>>>(feats, featsb);

    float* out = (float*)d_out;
    if (use_stg) {
        conv_mfma_kernel<1><<<NBLK, 256, 0, stream>>>(featsb, Wb, srcmap, out, stg, pstats);
        stats_reduce_kernel<<<96, 256, 0, stream>>>(pstats, gamma, beta, scsh);
        apply_bn_bf16_kernel<<<2048, 256, 0, stream>>>(stg, out, scsh);
    } else {
        conv_mfma_kernel<0><<<NBLK, 256, 0, stream>>>(featsb, Wb, srcmap, out, stg, pstats);
        stats_reduce_kernel<<<96, 256, 0, stream>>>(pstats, gamma, beta, scsh);
        apply_bn_fp32_kernel<<<2048, 256, 0, stream>>>(out, scsh);
    }
}